// Round 19
// baseline (278.308 us; speedup 1.0000x reference)
//
#include <hip/hip_runtime.h>
#include <hip/hip_bf16.h>
#include <math.h>

#define Dm 1024
#define Hn 16
#define HDm 64
#define FFm 4096
#define Sn 2048
#define SEG 512
#define EPSV 1e-6f

typedef __attribute__((ext_vector_type(4))) float f32x4;
typedef __attribute__((ext_vector_type(8))) short s16x8;
typedef __attribute__((ext_vector_type(4))) short s16x4;

__device__ inline short f2bf(float f) {
  __hip_bfloat16 h = __float2bfloat16(f);
  short s;
  __builtin_memcpy(&s, &h, 2);
  return s;
}
__device__ inline float bf2f(short s) {
  unsigned u = ((unsigned)(unsigned short)s) << 16;
  float f;
  __builtin_memcpy(&f, &u, 4);
  return f;
}

__device__ inline float wred_sum(float v) {
#pragma unroll
  for (int m = 32; m > 0; m >>= 1) v += __shfl_xor(v, m, 64);
  return v;
}

// async global->LDS, 16B per lane. LDS dest is wave-uniform base + lane*16.
__device__ inline void gld16(const short* g, short* lds_base) {
  __builtin_amdgcn_global_load_lds(
      (const __attribute__((address_space(1))) void*)g,
      (__attribute__((address_space(3))) void*)lds_base, 16, 0, 0);
}

// ---------------- LayerNorm: fp32 in -> bf16 out ----------------
__global__ __launch_bounds__(256) void ln_kernel(const float* __restrict__ x,
                                                 const float* __restrict__ g,
                                                 const float* __restrict__ b,
                                                 short* __restrict__ out) {
  const int row = blockIdx.x;
  const int tid = threadIdx.x;
  f32x4 v = *reinterpret_cast<const f32x4*>(x + (size_t)row * Dm + tid * 4);
  float s1 = v.x + v.y + v.z + v.w;
  float s2 = v.x * v.x + v.y * v.y + v.z * v.z + v.w * v.w;
  s1 = wred_sum(s1);
  s2 = wred_sum(s2);
  __shared__ float t1[4], t2[4];
  if ((tid & 63) == 0) { t1[tid >> 6] = s1; t2[tid >> 6] = s2; }
  __syncthreads();
  s1 = t1[0] + t1[1] + t1[2] + t1[3];
  s2 = t2[0] + t2[1] + t2[2] + t2[3];
  const float mean = s1 * (1.0f / Dm);
  const float var = s2 * (1.0f / Dm) - mean * mean;
  const float rstd = rsqrtf(var + EPSV);
  f32x4 gv = *reinterpret_cast<const f32x4*>(g + tid * 4);
  f32x4 bv = *reinterpret_cast<const f32x4*>(b + tid * 4);
  s16x4 o;
#pragma unroll
  for (int j = 0; j < 4; ++j)
    o[j] = f2bf((v[j] - mean) * rstd * gv[j] + bv[j]);
  *reinterpret_cast<s16x4*>(out + (size_t)row * Dm + tid * 4) = o;
}

// ---- fused split-K reduce (bf16 partials) + residual + LayerNorm ----
template <int SPLIT>
__global__ __launch_bounds__(256) void redln_bf(const short* __restrict__ pb,
                                                const float* __restrict__ bias,
                                                const float* __restrict__ res,
                                                const float* __restrict__ g,
                                                const float* __restrict__ b,
                                                float* __restrict__ xout,
                                                short* __restrict__ h) {
  const int row = blockIdx.x;
  const int tid = threadIdx.x;
  const size_t idx = (size_t)row * Dm + tid * 4;
  f32x4 o = *reinterpret_cast<const f32x4*>(res + idx);
  o += *reinterpret_cast<const f32x4*>(bias + tid * 4);
#pragma unroll
  for (int s = 0; s < SPLIT; ++s) {
    s16x4 v = *reinterpret_cast<const s16x4*>(pb + (size_t)s * Sn * Dm + idx);
#pragma unroll
    for (int j = 0; j < 4; ++j) o[j] += bf2f(v[j]);
  }
  *reinterpret_cast<f32x4*>(xout + idx) = o;
  float s1 = o.x + o.y + o.z + o.w;
  float s2 = o.x * o.x + o.y * o.y + o.z * o.z + o.w * o.w;
  s1 = wred_sum(s1);
  s2 = wred_sum(s2);
  __shared__ float t1[4], t2[4];
  if ((tid & 63) == 0) { t1[tid >> 6] = s1; t2[tid >> 6] = s2; }
  __syncthreads();
  s1 = t1[0] + t1[1] + t1[2] + t1[3];
  s2 = t2[0] + t2[1] + t2[2] + t2[3];
  const float mean = s1 * (1.0f / Dm);
  const float var = s2 * (1.0f / Dm) - mean * mean;
  const float rstd = rsqrtf(var + EPSV);
  f32x4 gv = *reinterpret_cast<const f32x4*>(g + tid * 4);
  f32x4 bv = *reinterpret_cast<const f32x4*>(b + tid * 4);
  s16x4 ho;
#pragma unroll
  for (int j = 0; j < 4; ++j)
    ho[j] = f2bf((o[j] - mean) * rstd * gv[j] + bv[j]);
  *reinterpret_cast<s16x4*>(h + idx) = ho;
}

// ---- final split-K reduce (bf16 partials): out = sum + bias + res (fp32) ----
template <int SPLIT>
__global__ __launch_bounds__(256) void fcred_bf(const short* __restrict__ pb,
                                                const float* __restrict__ bias,
                                                const float* __restrict__ res,
                                                float* __restrict__ out) {
  const size_t i = ((size_t)blockIdx.x * 256 + threadIdx.x) * 4;
  f32x4 o = *reinterpret_cast<const f32x4*>(res + i);
  o += *reinterpret_cast<const f32x4*>(bias + (i & (Dm - 1)));
#pragma unroll
  for (int s = 0; s < SPLIT; ++s) {
    s16x4 v = *reinterpret_cast<const s16x4*>(pb + (size_t)s * Sn * Dm + i);
#pragma unroll
    for (int j = 0; j < 4; ++j) o[j] += bf2f(v[j]);
  }
  *reinterpret_cast<f32x4*>(out + i) = o;
}

// ---- merged weight transpose: all 8 W (K x N fp32) -> Wt (N x K bf16) ----
struct WtJobs {
  const float* src[8];
  short* dst[8];
  int K[8], N[8], start[9];
};
__global__ __launch_bounds__(256) void wtall_kernel(WtJobs jb) {
  __shared__ float t[32][33];
  const int bid = blockIdx.x;
  int j = 0;
#pragma unroll
  for (int q = 1; q < 8; ++q)
    if (bid >= jb.start[q]) j = q;
  const int local = bid - jb.start[j];
  const int K = jb.K[j], N = jb.N[j];
  const int nx = N >> 5;
  const int n0 = (local % nx) * 32, k0 = (local / nx) * 32;
  const float* W = jb.src[j];
  short* Wt = jb.dst[j];
  const int tx = threadIdx.x & 31, ty = threadIdx.x >> 5;
#pragma unroll
  for (int r = 0; r < 32; r += 8)
    t[r + ty][tx] = W[(size_t)(k0 + r + ty) * N + n0 + tx];
  __syncthreads();
#pragma unroll
  for (int r = 0; r < 32; r += 8)
    Wt[(size_t)(n0 + r + ty) * K + k0 + tx] = f2bf(t[tx][r + ty]);
}

// ---- V transpose to fragment-major: V rows k (stride ldv) -> vT2 ----
// vT2[((k>>5)*1024 + d)*32 + (k&31)]: PV B-frag reads become contiguous
// 1KB wave bursts.
__global__ __launch_bounds__(256) void wtb2_kernel(const short* __restrict__ V,
                                                   short* __restrict__ Vt2,
                                                   int ldv) {
  __shared__ short t[32][34];
  const int n0 = blockIdx.x * 32;       // d
  const int kb = blockIdx.y;            // k block of 32
  const int tx = threadIdx.x & 31, ty = threadIdx.x >> 5;
#pragma unroll
  for (int r = 0; r < 32; r += 8)
    t[r + ty][tx] = V[(size_t)(kb * 32 + r + ty) * ldv + n0 + tx];
  __syncthreads();
#pragma unroll
  for (int r = 0; r < 32; r += 8)
    Vt2[((size_t)kb * 1024 + n0 + r + ty) * 32 + tx] = t[tx][r + ty];
}

// ---------- attn3: minimal-sync fused attention, 2 blocks/CU ----------
// Block = 4 waves / 64 q-rows of one (seg,head); each wave owns 16 q x 512 k.
// LDS = K tile only (64 KB, coalesced gld16 + swizzle) -> 2 blocks/CU.
// Q direct to regs; V direct from global in fragment-major vT2 (coalesced).
// Softmax wave-local; P wave-private in the dead K region (4x16x512 = 64 KB,
// single pass); same-wave RAW via lgkmcnt(0)+sched_barrier. Two barriers.
// 1-D grid id = qblk*64 + z keeps a (seg,head)'s q-blocks on one XCD.
__global__ __launch_bounds__(256, 2) void attn3_kernel(const short* __restrict__ qkvb,
                                                       const short* __restrict__ vT2,
                                                       short* __restrict__ ao) {
  __shared__ short Ks[512 * 64];   // 64 KB; reused as P[64][512]
  const int tid = threadIdx.x;
  const int lane = tid & 63;
  const int wave = tid >> 6;              // 0..3
  const int l15 = lane & 15, lg = lane >> 4, rx = l15 & 7;
  const int qblk = blockIdx.x >> 6;       // 0..7
  const int z = blockIdx.x & 63;          // seg = z&3, head = z>>2
  const int seg = z & 3, head = z >> 2;
  const int qbase = seg * SEG + qblk * 64 + wave * 16;

  // Q first (2 loads), then K stage; vmcnt(0) covers both.
  const short* Qg = qkvb + (size_t)(qbase + l15) * 3072 + head * HDm + lg * 8;
  s16x8 qf0 = *reinterpret_cast<const s16x8*>(Qg);
  s16x8 qf1 = *reinterpret_cast<const s16x8*>(Qg + 32);
  __builtin_amdgcn_sched_barrier(0);
  const int srow = tid >> 3;                     // 0..31
  const int sch = ((tid & 7) ^ (srow & 7)) * 8;  // pre-swizzled source chunk
  const short* Kg = qkvb + (size_t)(seg * SEG + srow) * 3072 + Dm +
                    head * HDm + sch;
#pragma unroll
  for (int j = 0; j < 16; ++j)
    gld16(Kg + (size_t)(j * 32) * 3072, &Ks[(j * 32 + wave * 8) * 64]);
  asm volatile("s_waitcnt vmcnt(0)" ::: "memory");
  __builtin_amdgcn_s_barrier();
  __builtin_amdgcn_sched_barrier(0);

  // --- S = Q.K^T : acc[j] covers k cols j*16..+16, q rows = wave*16.. ---
  f32x4 acc[32];
#pragma unroll
  for (int j = 0; j < 32; ++j) acc[j] = f32x4{0.f, 0.f, 0.f, 0.f};
  __builtin_amdgcn_s_setprio(1);
#pragma unroll
  for (int j = 0; j < 32; ++j) {
    const int R = j * 16 + l15;
    s16x8 b0 = *reinterpret_cast<const s16x8*>(&Ks[R * 64 + ((lg ^ rx) << 3)]);
    s16x8 b1 = *reinterpret_cast<const s16x8*>(
        &Ks[R * 64 + (((lg + 4) ^ rx) << 3)]);
    acc[j] = __builtin_amdgcn_mfma_f32_16x16x32_bf16(qf0, b0, acc[j], 0, 0, 0);
    acc[j] = __builtin_amdgcn_mfma_f32_16x16x32_bf16(qf1, b1, acc[j], 0, 0, 0);
  }
  __builtin_amdgcn_s_setprio(0);

  // --- softmax, fully wave-local (q = lg*4+r; k over (j, l15)) ---
  float mx[4], inv[4];
#pragma unroll
  for (int r = 0; r < 4; ++r) {
    float m = acc[0][r];
#pragma unroll
    for (int j = 1; j < 32; ++j) m = fmaxf(m, acc[j][r]);
#pragma unroll
    for (int d = 1; d < 16; d <<= 1) m = fmaxf(m, __shfl_xor(m, d, 64));
    mx[r] = m * 0.125f;
  }
#pragma unroll
  for (int r = 0; r < 4; ++r) {
    float s = 0.f;
#pragma unroll
    for (int j = 0; j < 32; ++j) {
      float pv = __expf(acc[j][r] * 0.125f - mx[r]);
      acc[j][r] = pv;
      s += pv;
    }
#pragma unroll
    for (int d = 1; d < 16; d <<= 1) s += __shfl_xor(s, d, 64);
    inv[r] = 1.0f / s;
  }

  __syncthreads();  // all QK reads of Ks complete before P overwrites

  // --- P -> wave-private 16x512 region of Ks (swizzled both sides) ---
  short* Pw = Ks + wave * 16 * 512;
#pragma unroll
  for (int j = 0; j < 32; ++j) {
#pragma unroll
    for (int r = 0; r < 4; ++r) {
      const int q = lg * 4 + r;            // local row 0..15
      const int kp = j * 16 + l15;         // 0..511
      const int c = kp >> 3;
      const int sxw = (q ^ (q >> 3)) & 7;
      const int cs = (c & ~7) | ((c & 7) ^ sxw);
      Pw[q * 512 + cs * 8 + (kp & 7)] = f2bf(acc[j][r]);
    }
  }
  asm volatile("s_waitcnt lgkmcnt(0)" ::: "memory");
  __builtin_amdgcn_sched_barrier(0);

  // --- PV: A = P (row = l15, k = lg*8..), B = vT2 direct (coalesced) ---
  f32x4 pv[4] = {};
  const int sxr = (l15 ^ (l15 >> 3)) & 7;
  const short* Vg = vT2 + ((size_t)(seg * 16) * 1024 + head * HDm) * 32;
  __builtin_amdgcn_s_setprio(1);
#pragma unroll
  for (int ks = 0; ks < 16; ++ks) {
    const int ca = ks * 4 + lg;
    const int csa = (ca & ~7) | ((ca & 7) ^ sxr);
    s16x8 pa = *reinterpret_cast<const s16x8*>(&Pw[l15 * 512 + csa * 8]);
#pragma unroll
    for (int fj = 0; fj < 4; ++fj) {
      s16x8 pb = *reinterpret_cast<const s16x8*>(
          Vg + ((size_t)ks * 1024 + fj * 16 + l15) * 32 + lg * 8);
      pv[fj] = __builtin_amdgcn_mfma_f32_16x16x32_bf16(pa, pb, pv[fj], 0, 0, 0);
    }
  }
  __builtin_amdgcn_s_setprio(0);

  // --- output (row q = qbase + lg*4 + r), 1/sum from regs ---
#pragma unroll
  for (int r = 0; r < 4; ++r) {
    const float iv = inv[r];
    const size_t rowg = (size_t)(qbase + lg * 4 + r) * Dm + head * 64;
#pragma unroll
    for (int fj = 0; fj < 4; ++fj)
      ao[rowg + fj * 16 + l15] = f2bf(pv[fj][r] * iv);
  }
}

struct GemmArgs {
  const short* A; int lda;
  const short* B; int ldb;
  void* C; int ldc;
  int M, N, K;
  const float* bias;
  const float* cosb; const float* sinb;
  float scale;
};

// ---------- gemm6: 2-barrier m97 path, conflict-free, XCD-swizzled ----------
// MODE 4: dense + bias + RoPE (bf16). MODE 5: dense + bias + GELU (bf16).
// MODE 6: dense split-K (bf16 partials).
template <int BM, int BN, int SPLIT, int MODE>
__global__ __launch_bounds__(256) void gemm6(GemmArgs p) {
  constexpr int WN = 2;
  constexpr int WM = 2;
  constexpr int FI = BM / WM / 16;
  constexpr int FJ = BN / WN / 16;
  const int z = blockIdx.z;
  const short* A = p.A;
  const short* B = p.B;
  char* Cb = (char*)p.C;
  int kbase = 0, nkt = p.K >> 6;
  const int gx = gridDim.x;
  const int nwg = gx * gridDim.y;
  const int orig = blockIdx.y * gx + blockIdx.x;
  const int sid = (orig & 7) * (nwg >> 3) + (orig >> 3);
  const int tileM = (sid / gx) * BM;
  const int tileN = (sid % gx) * BN;
  if (MODE == 6) {
    kbase = z * (p.K / SPLIT);
    nkt = (p.K / SPLIT) >> 6;
    Cb += (size_t)z * p.M * p.N * 2;
  }
  __shared__ short As[BM * 64];
  __shared__ short Bs[BN * 64];
  const int tid = threadIdx.x;
  const int lane = tid & 63;
  const int wave = tid >> 6;
  const int l15 = lane & 15;
  const int lg = lane >> 4;
  const int rx = l15 & 7;
  const int wr = (wave / WN) * (BM / WM);
  const int wc = (wave % WN) * (BN / WN);
  const int srow = lane >> 3;
  const int scol = ((lane & 7) ^ srow) * 8;

  f32x4 acc[FI][FJ] = {};

  const short* Ag = A + (size_t)(tileM + wave * 8 + srow) * p.lda + scol + kbase;
  const short* Bg = B + (size_t)(tileN + wave * 8 + srow) * p.ldb + scol + kbase;

  for (int kt = 0; kt < nkt; ++kt) {
    const int k0 = kt * 64;
#pragma unroll
    for (int j = 0; j < BM / 32; ++j)
      gld16(Ag + (size_t)(j * 32) * p.lda + k0, &As[(j * 32 + wave * 8) * 64]);
#pragma unroll
    for (int j = 0; j < BN / 32; ++j)
      gld16(Bg + (size_t)(j * 32) * p.ldb + k0, &Bs[(j * 32 + wave * 8) * 64]);
    __syncthreads();
#pragma unroll
    for (int kk = 0; kk < 64; kk += 32) {
      const int kkc = kk >> 3;
      s16x8 af[FI], bfr[FJ];
#pragma unroll
      for (int f = 0; f < FI; ++f)
        af[f] = *reinterpret_cast<const s16x8*>(
            &As[(wr + f * 16 + l15) * 64 + (((lg + kkc) ^ rx) << 3)]);
#pragma unroll
      for (int f = 0; f < FJ; ++f)
        bfr[f] = *reinterpret_cast<const s16x8*>(
            &Bs[(wc + f * 16 + l15) * 64 + (((lg + kkc) ^ rx) << 3)]);
#pragma unroll
      for (int fi = 0; fi < FI; ++fi)
#pragma unroll
        for (int fj = 0; fj < FJ; ++fj)
          acc[fi][fj] = __builtin_amdgcn_mfma_f32_16x16x32_bf16(
              af[fi], bfr[fj], acc[fi][fj], 0, 0, 0);
    }
    __syncthreads();
  }

  if (MODE == 4) {
    short* Cs = (short*)Cb;
    const bool isqk = (tileN + wc) < 2048;
#pragma unroll
    for (int fi = 0; fi < FI; ++fi) {
#pragma unroll
      for (int fj = 0; fj < FJ; ++fj) {
#pragma unroll
        for (int r = 0; r < 4; ++r) {
          const int row = tileM + wr + fi * 16 + lg * 4 + r;
          const int col = tileN + wc + fj * 16 + l15;
          float a0 = acc[fi][fj][r] + p.bias[col];
          float vout;
          if (isqk) {
            float a1 = acc[fi][fj ^ 2][r] + p.bias[col ^ 32];
            const int dl = fj * 16 + l15;
            const float c = p.cosb[(size_t)row * HDm + dl];
            const float sn = p.sinb[(size_t)row * HDm + dl];
            vout = (fj < 2) ? (a0 * c - a1 * sn) : (a0 * c + a1 * sn);
          } else {
            vout = a0;
          }
          Cs[(size_t)row * p.ldc + col] = f2bf(vout);
        }
      }
    }
    return;
  }

#pragma unroll
  for (int fi = 0; fi < FI; ++fi) {
#pragma unroll
    for (int fj = 0; fj < FJ; ++fj) {
#pragma unroll
      for (int r = 0; r < 4; ++r) {
        const int row = tileM + wr + fi * 16 + lg * 4 + r;
        const int col = tileN + wc + fj * 16 + l15;
        float v = acc[fi][fj][r];
        if (MODE == 5) {
          v += p.bias[col];
          v = 0.5f * v * (1.0f + erff(v * 0.70710678118654752f));
        }
        reinterpret_cast<short*>(Cb)[(size_t)row * p.ldc + col] = f2bf(v);
      }
    }
  }
}

extern "C" void kernel_launch(void* const* d_in, const int* in_sizes, int n_in,
                              void* d_out, int out_size, void* d_ws, size_t ws_size,
                              hipStream_t stream) {
  const float* x0 = (const float*)d_in[0];
  const float* cosb = (const float*)d_in[2];
  const float* sinb = (const float*)d_in[3];
  const float* ln1_g = (const float*)d_in[4];
  const float* ln1_b = (const float*)d_in[5];
  const float* qkv_w = (const float*)d_in[6];
  const float* qkv_b = (const float*)d_in[7];
  const float* proj_w = (const float*)d_in[8];
  const float* proj_b = (const float*)d_in[9];
  const float* ln2_g = (const float*)d_in[10];
  const float* ln2_b = (const float*)d_in[11];
  const float* fc1_w = (const float*)d_in[12];
  const float* fc1_b = (const float*)d_in[13];
  const float* fc2_w = (const float*)d_in[14];
  const float* fc2_b = (const float*)d_in[15];

  char* ws = (char*)d_ws;
  size_t off = 0;
  auto alloc = [&](size_t bytes) {
    void* p = ws + off;
    off += (bytes + 255) & ~(size_t)255;
    return p;
  };
  short* wqkvT = (short*)alloc((size_t)2 * 3072 * 1024 * 2);
  short* wprojT = (short*)alloc((size_t)2 * 1024 * 1024 * 2);
  short* wfc1T = (short*)alloc((size_t)2 * 4096 * 1024 * 2);
  short* wfc2T = (short*)alloc((size_t)2 * 1024 * 4096 * 2);
  float* xbuf = (float*)alloc((size_t)Sn * Dm * 4);
  short* hbuf = (short*)alloc((size_t)Sn * Dm * 2);
  short* qkvb = (short*)alloc((size_t)Sn * 3 * Dm * 2);
  float* pbuf = (float*)alloc((size_t)4 * Sn * Dm * 4);
  short* pbufS = (short*)pbuf;
  short* ao = (short*)alloc((size_t)Sn * Dm * 2);
  short* ffn = (short*)alloc((size_t)Sn * FFm * 2);
  short* vT2 = ffn;  // vT2 (4.2MB) aliases ffn: dead during attention phase
  (void)ws_size; (void)in_sizes; (void)n_in; (void)out_size;

  {  // merged weight transpose+convert: 8 jobs, one dispatch
    WtJobs jb;
    int acc = 0;
    for (int i = 0; i < 2; ++i) {
      const int base = i * 4;
      jb.src[base + 0] = qkv_w + (size_t)i * Dm * 3072;
      jb.dst[base + 0] = wqkvT + (size_t)i * 3072 * Dm;
      jb.K[base + 0] = Dm; jb.N[base + 0] = 3072;
      jb.src[base + 1] = proj_w + (size_t)i * Dm * Dm;
      jb.dst[base + 1] = wprojT + (size_t)i * Dm * Dm;
      jb.K[base + 1] = Dm; jb.N[base + 1] = Dm;
      jb.src[base + 2] = fc1_w + (size_t)i * Dm * FFm;
      jb.dst[base + 2] = wfc1T + (size_t)i * FFm * Dm;
      jb.K[base + 2] = Dm; jb.N[base + 2] = FFm;
      jb.src[base + 3] = fc2_w + (size_t)i * FFm * Dm;
      jb.dst[base + 3] = wfc2T + (size_t)i * Dm * FFm;
      jb.K[base + 3] = FFm; jb.N[base + 3] = Dm;
    }
    for (int j = 0; j < 8; ++j) {
      jb.start[j] = acc;
      acc += (jb.N[j] >> 5) * (jb.K[j] >> 5);
    }
    jb.start[8] = acc;
    wtall_kernel<<<dim3(acc), 256, 0, stream>>>(jb);
  }

  // layer 0 LN1 (layer-boundary LNs are fused into the reduces)
  ln_kernel<<<dim3(Sn), 256, 0, stream>>>(x0, ln1_g, ln1_b, hbuf);

  for (int i = 0; i < 2; ++i) {
    const float* xin = i ? (const float*)xbuf : x0;

    {  // qkvb = rope(h @ Wqkv + b)  (64x128, grid 768 = 3/CU, bf16 out)
      GemmArgs p = {};
      p.A = hbuf; p.lda = Dm;
      p.B = wqkvT + (size_t)i * 3072 * Dm; p.ldb = Dm;
      p.C = qkvb; p.ldc = 3 * Dm;
      p.M = Sn; p.N = 3 * Dm; p.K = Dm;
      p.bias = qkv_b + i * 3 * Dm; p.cosb = cosb; p.sinb = sinb;
      gemm6<64, 128, 1, 4><<<dim3(24, 32, 1), 256, 0, stream>>>(p);
    }

    // v (bf16 cols 2048.. of qkvb) -> vT2 (fragment-major)
    wtb2_kernel<<<dim3(32, 64), 256, 0, stream>>>(qkvb + 2 * Dm, vT2, 3 * Dm);

    // ao = softmax(scale * q @ k^T) @ v  (minimal-sync, 2 blocks/CU)
    attn3_kernel<<<dim3(512), 256, 0, stream>>>(qkvb, vT2, ao);

    {  // proj partials = ao @ Wproj  (64x64 split-K=2, bf16, grid 1024)
      GemmArgs p = {};
      p.A = ao; p.lda = Dm;
      p.B = wprojT + (size_t)i * Dm * Dm; p.ldb = Dm;
      p.C = pbufS; p.ldc = Dm;
      p.M = Sn; p.N = Dm; p.K = Dm;
      gemm6<64, 64, 2, 6><<<dim3(16, 32, 2), 256, 0, stream>>>(p);
    }
    // x = xin + proj + bias ; h = LN2(x)
    redln_bf<2><<<dim3(Sn), 256, 0, stream>>>(
        pbufS, proj_b + i * Dm, xin, ln2_g + i * Dm, ln2_b + i * Dm, xbuf, hbuf);

    {  // ffn = gelu(h2 @ Wfc1 + b)  (64x128, grid 1024 = 4/CU, bf16 out)
      GemmArgs p = {};
      p.A = hbuf; p.lda = Dm;
      p.B = wfc1T + (size_t)i * FFm * Dm; p.ldb = Dm;
      p.C = ffn; p.ldc = FFm;
      p.M = Sn; p.N = FFm; p.K = Dm;
      p.bias = fc1_b + i * FFm;
      gemm6<64, 128, 1, 5><<<dim3(32, 32, 1), 256, 0, stream>>>(p);
    }

    {  // fc2 partials = ffn @ Wfc2  (64x128 split-K=4, bf16, grid 1024)
      GemmArgs p = {};
      p.A = ffn; p.lda = FFm;
      p.B = wfc2T + (size_t)i * Dm * FFm; p.ldb = FFm;
      p.C = pbufS; p.ldc = Dm;
      p.M = Sn; p.N = Dm; p.K = FFm;
      gemm6<64, 128, 4, 6><<<dim3(8, 32, 4), 256, 0, stream>>>(p);
    }
    if (i == 0) {
      // x = xbuf + fc2 + bias ; h = LN1[1](x)
      redln_bf<4><<<dim3(Sn), 256, 0, stream>>>(
          pbufS, fc2_b, xbuf, ln1_g + Dm, ln1_b + Dm, xbuf, hbuf);
    } else {
      fcred_bf<4><<<dim3(Sn * Dm / 1024), 256, 0, stream>>>(
          pbufS, fc2_b + Dm, xbuf, (float*)d_out);
    }
  }
}

// Round 20
// 271.675 us; speedup vs baseline: 1.0244x; 1.0244x over previous
//
#include <hip/hip_runtime.h>
#include <hip/hip_bf16.h>
#include <math.h>

#define Dm 1024
#define Hn 16
#define HDm 64
#define FFm 4096
#define Sn 2048
#define SEG 512
#define EPSV 1e-6f

typedef __attribute__((ext_vector_type(4))) float f32x4;
typedef __attribute__((ext_vector_type(8))) short s16x8;
typedef __attribute__((ext_vector_type(4))) short s16x4;

__device__ inline short f2bf(float f) {
  __hip_bfloat16 h = __float2bfloat16(f);
  short s;
  __builtin_memcpy(&s, &h, 2);
  return s;
}
__device__ inline float bf2f(short s) {
  unsigned u = ((unsigned)(unsigned short)s) << 16;
  float f;
  __builtin_memcpy(&f, &u, 4);
  return f;
}

__device__ inline float wred_sum(float v) {
#pragma unroll
  for (int m = 32; m > 0; m >>= 1) v += __shfl_xor(v, m, 64);
  return v;
}

// async global->LDS, 16B per lane. LDS dest is wave-uniform base + lane*16.
__device__ inline void gld16(const short* g, short* lds_base) {
  __builtin_amdgcn_global_load_lds(
      (const __attribute__((address_space(1))) void*)g,
      (__attribute__((address_space(3))) void*)lds_base, 16, 0, 0);
}

// ---------------- LayerNorm: fp32 in -> bf16 out ----------------
__global__ __launch_bounds__(256) void ln_kernel(const float* __restrict__ x,
                                                 const float* __restrict__ g,
                                                 const float* __restrict__ b,
                                                 short* __restrict__ out) {
  const int row = blockIdx.x;
  const int tid = threadIdx.x;
  f32x4 v = *reinterpret_cast<const f32x4*>(x + (size_t)row * Dm + tid * 4);
  float s1 = v.x + v.y + v.z + v.w;
  float s2 = v.x * v.x + v.y * v.y + v.z * v.z + v.w * v.w;
  s1 = wred_sum(s1);
  s2 = wred_sum(s2);
  __shared__ float t1[4], t2[4];
  if ((tid & 63) == 0) { t1[tid >> 6] = s1; t2[tid >> 6] = s2; }
  __syncthreads();
  s1 = t1[0] + t1[1] + t1[2] + t1[3];
  s2 = t2[0] + t2[1] + t2[2] + t2[3];
  const float mean = s1 * (1.0f / Dm);
  const float var = s2 * (1.0f / Dm) - mean * mean;
  const float rstd = rsqrtf(var + EPSV);
  f32x4 gv = *reinterpret_cast<const f32x4*>(g + tid * 4);
  f32x4 bv = *reinterpret_cast<const f32x4*>(b + tid * 4);
  s16x4 o;
#pragma unroll
  for (int j = 0; j < 4; ++j)
    o[j] = f2bf((v[j] - mean) * rstd * gv[j] + bv[j]);
  *reinterpret_cast<s16x4*>(out + (size_t)row * Dm + tid * 4) = o;
}

// ---- fused split-K reduce (bf16 partials) + residual + LayerNorm ----
template <int SPLIT>
__global__ __launch_bounds__(256) void redln_bf(const short* __restrict__ pb,
                                                const float* __restrict__ bias,
                                                const float* __restrict__ res,
                                                const float* __restrict__ g,
                                                const float* __restrict__ b,
                                                float* __restrict__ xout,
                                                short* __restrict__ h) {
  const int row = blockIdx.x;
  const int tid = threadIdx.x;
  const size_t idx = (size_t)row * Dm + tid * 4;
  f32x4 o = *reinterpret_cast<const f32x4*>(res + idx);
  o += *reinterpret_cast<const f32x4*>(bias + tid * 4);
#pragma unroll
  for (int s = 0; s < SPLIT; ++s) {
    s16x4 v = *reinterpret_cast<const s16x4*>(pb + (size_t)s * Sn * Dm + idx);
#pragma unroll
    for (int j = 0; j < 4; ++j) o[j] += bf2f(v[j]);
  }
  *reinterpret_cast<f32x4*>(xout + idx) = o;
  float s1 = o.x + o.y + o.z + o.w;
  float s2 = o.x * o.x + o.y * o.y + o.z * o.z + o.w * o.w;
  s1 = wred_sum(s1);
  s2 = wred_sum(s2);
  __shared__ float t1[4], t2[4];
  if ((tid & 63) == 0) { t1[tid >> 6] = s1; t2[tid >> 6] = s2; }
  __syncthreads();
  s1 = t1[0] + t1[1] + t1[2] + t1[3];
  s2 = t2[0] + t2[1] + t2[2] + t2[3];
  const float mean = s1 * (1.0f / Dm);
  const float var = s2 * (1.0f / Dm) - mean * mean;
  const float rstd = rsqrtf(var + EPSV);
  f32x4 gv = *reinterpret_cast<const f32x4*>(g + tid * 4);
  f32x4 bv = *reinterpret_cast<const f32x4*>(b + tid * 4);
  s16x4 ho;
#pragma unroll
  for (int j = 0; j < 4; ++j)
    ho[j] = f2bf((o[j] - mean) * rstd * gv[j] + bv[j]);
  *reinterpret_cast<s16x4*>(h + idx) = ho;
}

// ---- final split-K reduce (bf16 partials): out = sum + bias + res (fp32) ----
template <int SPLIT>
__global__ __launch_bounds__(256) void fcred_bf(const short* __restrict__ pb,
                                                const float* __restrict__ bias,
                                                const float* __restrict__ res,
                                                float* __restrict__ out) {
  const size_t i = ((size_t)blockIdx.x * 256 + threadIdx.x) * 4;
  f32x4 o = *reinterpret_cast<const f32x4*>(res + i);
  o += *reinterpret_cast<const f32x4*>(bias + (i & (Dm - 1)));
#pragma unroll
  for (int s = 0; s < SPLIT; ++s) {
    s16x4 v = *reinterpret_cast<const s16x4*>(pb + (size_t)s * Sn * Dm + i);
#pragma unroll
    for (int j = 0; j < 4; ++j) o[j] += bf2f(v[j]);
  }
  *reinterpret_cast<f32x4*>(out + i) = o;
}

// ---- merged weight transpose: all 8 W (K x N fp32) -> Wt (N x K bf16) ----
struct WtJobs {
  const float* src[8];
  short* dst[8];
  int K[8], N[8], start[9];
};
__global__ __launch_bounds__(256) void wtall_kernel(WtJobs jb) {
  __shared__ float t[32][33];
  const int bid = blockIdx.x;
  int j = 0;
#pragma unroll
  for (int q = 1; q < 8; ++q)
    if (bid >= jb.start[q]) j = q;
  const int local = bid - jb.start[j];
  const int K = jb.K[j], N = jb.N[j];
  const int nx = N >> 5;
  const int n0 = (local % nx) * 32, k0 = (local / nx) * 32;
  const float* W = jb.src[j];
  short* Wt = jb.dst[j];
  const int tx = threadIdx.x & 31, ty = threadIdx.x >> 5;
#pragma unroll
  for (int r = 0; r < 32; r += 8)
    t[r + ty][tx] = W[(size_t)(k0 + r + ty) * N + n0 + tx];
  __syncthreads();
#pragma unroll
  for (int r = 0; r < 32; r += 8)
    Wt[(size_t)(n0 + r + ty) * K + k0 + tx] = f2bf(t[tx][r + ty]);
}

// ---- bf16 transpose: V (K x N bf16, row stride ldv) -> Vt (N x K bf16) ----
__global__ __launch_bounds__(256) void wtb_kernel(const short* __restrict__ V,
                                                  short* __restrict__ Vt,
                                                  int K, int N, int ldv) {
  __shared__ short t[32][34];
  const int n0 = blockIdx.x * 32, k0 = blockIdx.y * 32;
  const int tx = threadIdx.x & 31, ty = threadIdx.x >> 5;
#pragma unroll
  for (int r = 0; r < 32; r += 8)
    t[r + ty][tx] = V[(size_t)(k0 + r + ty) * ldv + n0 + tx];
  __syncthreads();
#pragma unroll
  for (int r = 0; r < 32; r += 8)
    Vt[(size_t)(n0 + r + ty) * K + k0 + tx] = t[tx][r + ty];
}

// ---------- qksoftpv: fused attention, minimal-sync full-row waves ----------
// Each of 8 waves owns 16 q-rows x full 512 k. Softmax wave-local (16-lane
// shfl). P is wave-PRIVATE (own 16 rows of the reused Ks region, two 256-col
// halves); same-wave RAW/WAR ordered by lgkmcnt(0)+sched_barrier. Only TWO
// block barriers: post-stage and post-QK (Ks WAR). 1-D grid id = qblk*64+z
// keeps the 4 q-blocks of a (seg,head) on one XCD.
__global__ __launch_bounds__(512, 2) void qksoftpv_kernel(const short* __restrict__ qkvb,
                                                          const short* __restrict__ vT,
                                                          short* __restrict__ ao) {
  __shared__ short Ks[512 * 64];   // 64 KB; reused as P[128][256] per half
  __shared__ short Vs[64 * 512];   // 64 KB: V^T rows d, cols k (swizzled)
  const int tid = threadIdx.x;
  const int lane = tid & 63;
  const int wave = tid >> 6;              // 0..7
  const int l15 = lane & 15, lg = lane >> 4, rx = l15 & 7;
  const int qblk = blockIdx.x >> 6;       // 0..3
  const int z = blockIdx.x & 63;          // seg = z&3, head = z>>2
  const int seg = z & 3, head = z >> 2;

  const int srow = tid >> 3;              // 0..63
  const int sch = ((tid & 7) ^ (srow & 7)) * 8;  // pre-swizzled source chunk

  // --- issue order pinned: Q(2) -> K(8) -> V(8); vmcnt(8) covers Q+K ---
  const short* Qg = qkvb +
      (size_t)(seg * SEG + qblk * 128 + wave * 16 + l15) * 3072 + head * HDm +
      lg * 8;
  s16x8 qf0 = *reinterpret_cast<const s16x8*>(Qg);
  s16x8 qf1 = *reinterpret_cast<const s16x8*>(Qg + 32);
  __builtin_amdgcn_sched_barrier(0);
  const short* Kg = qkvb + (size_t)(seg * SEG + srow) * 3072 + Dm +
                    head * HDm + sch;
#pragma unroll
  for (int j = 0; j < 8; ++j)
    gld16(Kg + (size_t)(j * 64) * 3072, &Ks[(j * 64 + wave * 8) * 64]);
  __builtin_amdgcn_sched_barrier(0);
  {
    const short* Vg = vT + (size_t)(head * 64) * Sn + seg * SEG;
#pragma unroll
    for (int j = 0; j < 8; ++j) {
      const int d = j * 8 + wave;
      const int c = (lane & ~7) | ((lane & 7) ^ (d & 7));
      gld16(Vg + (size_t)d * Sn + c * 8, &Vs[d * 512]);
    }
  }
  asm volatile("s_waitcnt vmcnt(8)" ::: "memory");  // Q+K done; V in flight
  __builtin_amdgcn_s_barrier();
  __builtin_amdgcn_sched_barrier(0);

  // --- S = Q.K^T : acc[j] covers k cols j*16..+16, q rows = wave*16.. ---
  f32x4 acc[32];
#pragma unroll
  for (int j = 0; j < 32; ++j) acc[j] = f32x4{0.f, 0.f, 0.f, 0.f};
  __builtin_amdgcn_s_setprio(1);
#pragma unroll
  for (int j = 0; j < 32; ++j) {
    const int R = j * 16 + l15;
    s16x8 b0 = *reinterpret_cast<const s16x8*>(&Ks[R * 64 + ((lg ^ rx) << 3)]);
    s16x8 b1 = *reinterpret_cast<const s16x8*>(
        &Ks[R * 64 + (((lg + 4) ^ rx) << 3)]);
    acc[j] = __builtin_amdgcn_mfma_f32_16x16x32_bf16(qf0, b0, acc[j], 0, 0, 0);
    acc[j] = __builtin_amdgcn_mfma_f32_16x16x32_bf16(qf1, b1, acc[j], 0, 0, 0);
  }
  __builtin_amdgcn_s_setprio(0);

  // --- softmax, fully wave-local (q = lg*4+r; k over (j, l15)) ---
  float mx[4], inv[4];
#pragma unroll
  for (int r = 0; r < 4; ++r) {
    float m = acc[0][r];
#pragma unroll
    for (int j = 1; j < 32; ++j) m = fmaxf(m, acc[j][r]);
#pragma unroll
    for (int d = 1; d < 16; d <<= 1) m = fmaxf(m, __shfl_xor(m, d, 64));
    mx[r] = m * 0.125f;
  }
#pragma unroll
  for (int r = 0; r < 4; ++r) {
    float s = 0.f;
#pragma unroll
    for (int j = 0; j < 32; ++j) {
      float pv = __expf(acc[j][r] * 0.125f - mx[r]);
      acc[j][r] = pv;
      s += pv;
    }
#pragma unroll
    for (int d = 1; d < 16; d <<= 1) s += __shfl_xor(s, d, 64);
    inv[r] = 1.0f / s;
  }

  __syncthreads();  // all QK reads of Ks complete before P overwrites
  asm volatile("s_waitcnt vmcnt(0)" ::: "memory");  // V resident

  // --- PV over two 256-col halves; P wave-private in Ks ---
  short* Ps = Ks;                        // P[128 q][256 k] per half
  f32x4 pv[4] = {};
  const int q2 = wave * 16 + l15;        // PV A-frag row
  const int sxr = (q2 ^ (q2 >> 3)) & 7;
#pragma unroll
  for (int kh = 0; kh < 2; ++kh) {
    // write own 16 rows x 256 cols (frags j = kh*16 .. +16)
#pragma unroll
    for (int jj = 0; jj < 16; ++jj) {
      const int j = kh * 16 + jj;
#pragma unroll
      for (int r = 0; r < 4; ++r) {
        const int q = wave * 16 + lg * 4 + r;
        const int kp = jj * 16 + l15;    // 0..255
        const int c = kp >> 3;
        const int sxw = (q ^ (q >> 3)) & 7;
        const int cs = (c & 24) | ((c & 7) ^ sxw);
        Ps[q * 256 + cs * 8 + (kp & 7)] = f2bf(acc[j][r]);
      }
    }
    asm volatile("s_waitcnt lgkmcnt(0)" ::: "memory");
    __builtin_amdgcn_sched_barrier(0);
    __builtin_amdgcn_s_setprio(1);
#pragma unroll
    for (int ks = 0; ks < 8; ++ks) {
      const int ca = ks * 4 + lg;
      const int csa = (ca & 24) | ((ca & 7) ^ sxr);
      s16x8 pa = *reinterpret_cast<const s16x8*>(&Ps[q2 * 256 + csa * 8]);
#pragma unroll
      for (int fj = 0; fj < 4; ++fj) {
        const int d = fj * 16 + l15;
        const int cb = kh * 32 + ks * 4 + lg;
        const int csb = (cb & ~7) | ((cb & 7) ^ (d & 7));
        s16x8 pb = *reinterpret_cast<const s16x8*>(&Vs[d * 512 + csb * 8]);
        pv[fj] = __builtin_amdgcn_mfma_f32_16x16x32_bf16(pa, pb, pv[fj], 0, 0, 0);
      }
    }
    __builtin_amdgcn_s_setprio(0);
    asm volatile("s_waitcnt lgkmcnt(0)" ::: "memory");  // own reads before next writes
    __builtin_amdgcn_sched_barrier(0);
  }

  // --- output (row q = wave*16 + lg*4 + r), 1/sum from regs ---
#pragma unroll
  for (int r = 0; r < 4; ++r) {
    const float iv = inv[r];
    const size_t rowg =
        (size_t)(seg * SEG + qblk * 128 + wave * 16 + lg * 4 + r) * Dm +
        head * 64;
#pragma unroll
    for (int fj = 0; fj < 4; ++fj)
      ao[rowg + fj * 16 + l15] = f2bf(pv[fj][r] * iv);
  }
}

struct GemmArgs {
  const short* A; int lda;
  const short* B; int ldb;
  void* C; int ldc;
  int M, N, K;
  const float* bias;
  const float* cosb; const float* sinb;
  float scale;
};

// ---------- gemm6: 2-barrier m97 path, conflict-free, XCD-swizzled ----------
// MODE 4: dense + bias + RoPE (bf16). MODE 5: dense + bias + GELU (bf16).
// MODE 6: dense split-K (bf16 partials).
template <int BM, int BN, int SPLIT, int MODE>
__global__ __launch_bounds__(256) void gemm6(GemmArgs p) {
  constexpr int WN = 2;
  constexpr int WM = 2;
  constexpr int FI = BM / WM / 16;
  constexpr int FJ = BN / WN / 16;
  const int z = blockIdx.z;
  const short* A = p.A;
  const short* B = p.B;
  char* Cb = (char*)p.C;
  int kbase = 0, nkt = p.K >> 6;
  const int gx = gridDim.x;
  const int nwg = gx * gridDim.y;
  const int orig = blockIdx.y * gx + blockIdx.x;
  const int sid = (orig & 7) * (nwg >> 3) + (orig >> 3);
  const int tileM = (sid / gx) * BM;
  const int tileN = (sid % gx) * BN;
  if (MODE == 6) {
    kbase = z * (p.K / SPLIT);
    nkt = (p.K / SPLIT) >> 6;
    Cb += (size_t)z * p.M * p.N * 2;
  }
  __shared__ short As[BM * 64];
  __shared__ short Bs[BN * 64];
  const int tid = threadIdx.x;
  const int lane = tid & 63;
  const int wave = tid >> 6;
  const int l15 = lane & 15;
  const int lg = lane >> 4;
  const int rx = l15 & 7;
  const int wr = (wave / WN) * (BM / WM);
  const int wc = (wave % WN) * (BN / WN);
  const int srow = lane >> 3;
  const int scol = ((lane & 7) ^ srow) * 8;

  f32x4 acc[FI][FJ] = {};

  const short* Ag = A + (size_t)(tileM + wave * 8 + srow) * p.lda + scol + kbase;
  const short* Bg = B + (size_t)(tileN + wave * 8 + srow) * p.ldb + scol + kbase;

  for (int kt = 0; kt < nkt; ++kt) {
    const int k0 = kt * 64;
#pragma unroll
    for (int j = 0; j < BM / 32; ++j)
      gld16(Ag + (size_t)(j * 32) * p.lda + k0, &As[(j * 32 + wave * 8) * 64]);
#pragma unroll
    for (int j = 0; j < BN / 32; ++j)
      gld16(Bg + (size_t)(j * 32) * p.ldb + k0, &Bs[(j * 32 + wave * 8) * 64]);
    __syncthreads();
#pragma unroll
    for (int kk = 0; kk < 64; kk += 32) {
      const int kkc = kk >> 3;
      s16x8 af[FI], bfr[FJ];
#pragma unroll
      for (int f = 0; f < FI; ++f)
        af[f] = *reinterpret_cast<const s16x8*>(
            &As[(wr + f * 16 + l15) * 64 + (((lg + kkc) ^ rx) << 3)]);
#pragma unroll
      for (int f = 0; f < FJ; ++f)
        bfr[f] = *reinterpret_cast<const s16x8*>(
            &Bs[(wc + f * 16 + l15) * 64 + (((lg + kkc) ^ rx) << 3)]);
#pragma unroll
      for (int fi = 0; fi < FI; ++fi)
#pragma unroll
        for (int fj = 0; fj < FJ; ++fj)
          acc[fi][fj] = __builtin_amdgcn_mfma_f32_16x16x32_bf16(
              af[fi], bfr[fj], acc[fi][fj], 0, 0, 0);
    }
    __syncthreads();
  }

  if (MODE == 4) {
    short* Cs = (short*)Cb;
    const bool isqk = (tileN + wc) < 2048;
#pragma unroll
    for (int fi = 0; fi < FI; ++fi) {
#pragma unroll
      for (int fj = 0; fj < FJ; ++fj) {
#pragma unroll
        for (int r = 0; r < 4; ++r) {
          const int row = tileM + wr + fi * 16 + lg * 4 + r;
          const int col = tileN + wc + fj * 16 + l15;
          float a0 = acc[fi][fj][r] + p.bias[col];
          float vout;
          if (isqk) {
            float a1 = acc[fi][fj ^ 2][r] + p.bias[col ^ 32];
            const int dl = fj * 16 + l15;
            const float c = p.cosb[(size_t)row * HDm + dl];
            const float sn = p.sinb[(size_t)row * HDm + dl];
            vout = (fj < 2) ? (a0 * c - a1 * sn) : (a0 * c + a1 * sn);
          } else {
            vout = a0;
          }
          Cs[(size_t)row * p.ldc + col] = f2bf(vout);
        }
      }
    }
    return;
  }

#pragma unroll
  for (int fi = 0; fi < FI; ++fi) {
#pragma unroll
    for (int fj = 0; fj < FJ; ++fj) {
#pragma unroll
      for (int r = 0; r < 4; ++r) {
        const int row = tileM + wr + fi * 16 + lg * 4 + r;
        const int col = tileN + wc + fj * 16 + l15;
        float v = acc[fi][fj][r];
        if (MODE == 5) {
          v += p.bias[col];
          v = 0.5f * v * (1.0f + erff(v * 0.70710678118654752f));
        }
        reinterpret_cast<short*>(Cb)[(size_t)row * p.ldc + col] = f2bf(v);
      }
    }
  }
}

extern "C" void kernel_launch(void* const* d_in, const int* in_sizes, int n_in,
                              void* d_out, int out_size, void* d_ws, size_t ws_size,
                              hipStream_t stream) {
  const float* x0 = (const float*)d_in[0];
  const float* cosb = (const float*)d_in[2];
  const float* sinb = (const float*)d_in[3];
  const float* ln1_g = (const float*)d_in[4];
  const float* ln1_b = (const float*)d_in[5];
  const float* qkv_w = (const float*)d_in[6];
  const float* qkv_b = (const float*)d_in[7];
  const float* proj_w = (const float*)d_in[8];
  const float* proj_b = (const float*)d_in[9];
  const float* ln2_g = (const float*)d_in[10];
  const float* ln2_b = (const float*)d_in[11];
  const float* fc1_w = (const float*)d_in[12];
  const float* fc1_b = (const float*)d_in[13];
  const float* fc2_w = (const float*)d_in[14];
  const float* fc2_b = (const float*)d_in[15];

  char* ws = (char*)d_ws;
  size_t off = 0;
  auto alloc = [&](size_t bytes) {
    void* p = ws + off;
    off += (bytes + 255) & ~(size_t)255;
    return p;
  };
  short* wqkvT = (short*)alloc((size_t)2 * 3072 * 1024 * 2);
  short* wprojT = (short*)alloc((size_t)2 * 1024 * 1024 * 2);
  short* wfc1T = (short*)alloc((size_t)2 * 4096 * 1024 * 2);
  short* wfc2T = (short*)alloc((size_t)2 * 1024 * 4096 * 2);
  float* xbuf = (float*)alloc((size_t)Sn * Dm * 4);
  short* hbuf = (short*)alloc((size_t)Sn * Dm * 2);
  short* qkvb = (short*)alloc((size_t)Sn * 3 * Dm * 2);
  float* pbuf = (float*)alloc((size_t)4 * Sn * Dm * 4);
  short* pbufS = (short*)pbuf;
  short* ao = (short*)alloc((size_t)Sn * Dm * 2);
  short* ffn = (short*)alloc((size_t)Sn * FFm * 2);
  short* vT = ffn;  // vT aliases ffn: dead during attention phase
  (void)ws_size; (void)in_sizes; (void)n_in; (void)out_size;

  {  // merged weight transpose+convert: 8 jobs, one dispatch
    WtJobs jb;
    int acc = 0;
    for (int i = 0; i < 2; ++i) {
      const int base = i * 4;
      jb.src[base + 0] = qkv_w + (size_t)i * Dm * 3072;
      jb.dst[base + 0] = wqkvT + (size_t)i * 3072 * Dm;
      jb.K[base + 0] = Dm; jb.N[base + 0] = 3072;
      jb.src[base + 1] = proj_w + (size_t)i * Dm * Dm;
      jb.dst[base + 1] = wprojT + (size_t)i * Dm * Dm;
      jb.K[base + 1] = Dm; jb.N[base + 1] = Dm;
      jb.src[base + 2] = fc1_w + (size_t)i * Dm * FFm;
      jb.dst[base + 2] = wfc1T + (size_t)i * FFm * Dm;
      jb.K[base + 2] = Dm; jb.N[base + 2] = FFm;
      jb.src[base + 3] = fc2_w + (size_t)i * FFm * Dm;
      jb.dst[base + 3] = wfc2T + (size_t)i * Dm * FFm;
      jb.K[base + 3] = FFm; jb.N[base + 3] = Dm;
    }
    for (int j = 0; j < 8; ++j) {
      jb.start[j] = acc;
      acc += (jb.N[j] >> 5) * (jb.K[j] >> 5);
    }
    jb.start[8] = acc;
    wtall_kernel<<<dim3(acc), 256, 0, stream>>>(jb);
  }

  // layer 0 LN1 (layer-boundary LNs are fused into the reduces)
  ln_kernel<<<dim3(Sn), 256, 0, stream>>>(x0, ln1_g, ln1_b, hbuf);

  for (int i = 0; i < 2; ++i) {
    const float* xin = i ? (const float*)xbuf : x0;

    {  // qkvb = rope(h @ Wqkv + b)  (64x128, grid 768 = 3/CU, bf16 out)
      GemmArgs p = {};
      p.A = hbuf; p.lda = Dm;
      p.B = wqkvT + (size_t)i * 3072 * Dm; p.ldb = Dm;
      p.C = qkvb; p.ldc = 3 * Dm;
      p.M = Sn; p.N = 3 * Dm; p.K = Dm;
      p.bias = qkv_b + i * 3 * Dm; p.cosb = cosb; p.sinb = sinb;
      gemm6<64, 128, 1, 4><<<dim3(24, 32, 1), 256, 0, stream>>>(p);
    }

    // v (bf16 cols 2048.. of qkvb) -> vT
    wtb_kernel<<<dim3(32, 64), 256, 0, stream>>>(qkvb + 2 * Dm, vT, Sn, Dm, 3 * Dm);

    // ao = softmax(scale * q @ k^T) @ v  (minimal-sync fused attention)
    qksoftpv_kernel<<<dim3(256), 512, 0, stream>>>(qkvb, vT, ao);

    {  // proj partials = ao @ Wproj  (64x64 split-K=2, bf16, grid 1024)
      GemmArgs p = {};
      p.A = ao; p.lda = Dm;
      p.B = wprojT + (size_t)i * Dm * Dm; p.ldb = Dm;
      p.C = pbufS; p.ldc = Dm;
      p.M = Sn; p.N = Dm; p.K = Dm;
      gemm6<64, 64, 2, 6><<<dim3(16, 32, 2), 256, 0, stream>>>(p);
    }
    // x = xin + proj + bias ; h = LN2(x)
    redln_bf<2><<<dim3(Sn), 256, 0, stream>>>(
        pbufS, proj_b + i * Dm, xin, ln2_g + i * Dm, ln2_b + i * Dm, xbuf, hbuf);

    {  // ffn = gelu(h2 @ Wfc1 + b)  (64x128, grid 1024 = 4/CU, bf16 out)
      GemmArgs p = {};
      p.A = hbuf; p.lda = Dm;
      p.B = wfc1T + (size_t)i * FFm * Dm; p.ldb = Dm;
      p.C = ffn; p.ldc = FFm;
      p.M = Sn; p.N = FFm; p.K = Dm;
      p.bias = fc1_b + i * FFm;
      gemm6<64, 128, 1, 5><<<dim3(32, 32, 1), 256, 0, stream>>>(p);
    }

    {  // fc2 partials = ffn @ Wfc2  (64x128 split-K=4, bf16, grid 1024)
      GemmArgs p = {};
      p.A = ffn; p.lda = FFm;
      p.B = wfc2T + (size_t)i * Dm * FFm; p.ldb = FFm;
      p.C = pbufS; p.ldc = Dm;
      p.M = Sn; p.N = Dm; p.K = FFm;
      gemm6<64, 128, 4, 6><<<dim3(8, 32, 4), 256, 0, stream>>>(p);
    }
    if (i == 0) {
      // x = xbuf + fc2 + bias ; h = LN1[1](x)
      redln_bf<4><<<dim3(Sn), 256, 0, stream>>>(
          pbufS, fc2_b, xbuf, ln1_g + Dm, ln1_b + Dm, xbuf, hbuf);
    } else {
      fcred_bf<4><<<dim3(Sn * Dm / 1024), 256, 0, stream>>>(
          pbufS, fc2_b + Dm, xbuf, (float*)d_out);
    }
  }
}